// Round 1
// baseline (3094.245 us; speedup 1.0000x reference)
//
#include <hip/hip_runtime.h>
#include <cmath>

// Problem constants
// B=256, T=48, N=4 -> N2=16, E=64, H=128, G=4H=512, S=64 (16x16 cells)

__device__ __forceinline__ float sigf(float x){ return 1.0f/(1.0f+expf(-x)); }

// ---------------- downsample + embed: emb[b][t][cell][e]  (B,T,16,64) ----------------
__global__ void k_ds(const float* __restrict__ x, const float* __restrict__ Wd,
                     const float* __restrict__ bd, float* __restrict__ emb){
  const int bid = blockIdx.x;                 // b*T + t
  const int tid = threadIdx.x;
  const float* xp = x + (size_t)bid * 4096;   // (B,1,T,64,64) flat
  __shared__ float s_sum[16][65], s_max[16][65], s_min[16][65];
  const int cj = (tid & 63) >> 4;
  const int slot = (tid >> 6) * 16 + (tid & 15);
  #pragma unroll
  for (int ci = 0; ci < 4; ++ci){
    float sm = 0.f, mx = -1e30f, mn = 1e30f;
    #pragma unroll
    for (int ii = 0; ii < 4; ++ii){
      float v = xp[(ci*4 + ii) * 256 + tid];  // row = ci*4+ii)*4 + tid>>6, col = tid&63
      sm += v; mx = fmaxf(mx, v); mn = fminf(mn, v);
    }
    s_sum[ci*4+cj][slot] = sm; s_max[ci*4+cj][slot] = mx; s_min[ci*4+cj][slot] = mn;
  }
  __syncthreads();
  __shared__ float c_mean[16], c_max[16], c_min[16];
  {
    const int cell = tid >> 4, l = tid & 15;
    float sm = 0.f, mx = -1e30f, mn = 1e30f;
    #pragma unroll
    for (int k = 0; k < 4; ++k){
      int s2 = l + k*16;
      sm += s_sum[cell][s2]; mx = fmaxf(mx, s_max[cell][s2]); mn = fminf(mn, s_min[cell][s2]);
    }
    #pragma unroll
    for (int m = 8; m >= 1; m >>= 1){
      sm += __shfl_xor(sm, m, 16);
      mx = fmaxf(mx, __shfl_xor(mx, m, 16));
      mn = fminf(mn, __shfl_xor(mn, m, 16));
    }
    if (l == 0){ c_mean[cell] = sm * (1.0f/256.0f); c_max[cell] = mx; c_min[cell] = mn; }
  }
  __syncthreads();
  const int e = tid & 63;
  const float w0 = Wd[e], w1 = Wd[64+e], w2 = Wd[128+e], bde = bd[e];
  float* ep = emb + (size_t)bid * 1024;
  #pragma unroll
  for (int k = 0; k < 4; ++k){
    int cell = (tid >> 6) * 4 + k;
    float v = c_mean[cell]*w0 + c_max[cell]*w1 + c_min[cell]*w2 + bde;
    ep[cell*64 + e] = fmaxf(v, 0.f);
  }
}

// ---------------- social reduce: social[b][e] = relu(bs + sum_n psoc[n][b][e]) ----------------
__global__ void k_socred(const float* __restrict__ psoc, const float* __restrict__ bs,
                         float* __restrict__ social){
  int idx = blockIdx.x * 256 + threadIdx.x;   // 16384
  int e = idx & 63;
  float s = bs[e];
  #pragma unroll
  for (int nn = 0; nn < 16; ++nn) s += psoc[(size_t)nn*16384 + idx];
  social[idx] = fmaxf(s, 0.f);
}

// ---------------- gates: block = (n, gc); computes gates[b][n][gc*32..+32] for all b ----------------
__global__ __launch_bounds__(512) void k_gates(
    const float* __restrict__ emb, const float* __restrict__ social,
    const float* __restrict__ hst, const float* __restrict__ W_ih,
    const float* __restrict__ W_hh, const float* __restrict__ b_ih,
    const float* __restrict__ b_hh, float* __restrict__ gates, int t){
  const int n = blockIdx.x >> 4, gc = blockIdx.x & 15;
  const int tid = threadIdx.x;
  __shared__ float sW[2][32*129];
  __shared__ float sX[128*129];
  #pragma unroll
  for (int j = 0; j < 16; ++j){
    int idx = j*512 + tid;                    // 8192 weight elems
    int which = idx >> 12, rem = idx & 4095;
    int g = rem >> 7, k = rem & 127;
    const float* src = which ? W_hh : W_ih;
    sW[which][g*129 + k] = src[((size_t)n*512 + gc*32 + g)*128 + k];
  }
  const int gq = tid & 15, bq = tid >> 4;     // 2 g's, 4 b's per thread
  const int gg = n*512 + gc*32 + gq*2;
  const float bias0 = b_ih[gg] + b_hh[gg];
  const float bias1 = b_ih[gg+1] + b_hh[gg+1];
  for (int ch = 0; ch < 2; ++ch){
    const int b0 = ch * 128;
    __syncthreads();
    #pragma unroll
    for (int j = 0; j < 32; ++j){             // stage frame||social
      int idx = j*512 + tid;                  // 16384
      int bb2 = idx >> 7, kk = idx & 127;
      float v = (kk < 64) ? emb[((size_t)(b0+bb2)*48 + t)*1024 + n*64 + kk]
                          : social[(b0+bb2)*64 + (kk-64)];
      sX[bb2*129 + kk] = v;
    }
    __syncthreads();
    float acc[2][4] = {};
    #pragma unroll 4
    for (int k = 0; k < 128; ++k){
      float w0 = sW[0][(gq*2+0)*129 + k];
      float w1 = sW[0][(gq*2+1)*129 + k];
      #pragma unroll
      for (int j = 0; j < 4; ++j){
        float xv = sX[(bq*4+j)*129 + k];
        acc[0][j] = fmaf(w0, xv, acc[0][j]);
        acc[1][j] = fmaf(w1, xv, acc[1][j]);
      }
    }
    __syncthreads();
    #pragma unroll
    for (int j = 0; j < 32; ++j){             // stage h
      int idx = j*512 + tid;
      int bb2 = idx >> 7, kk = idx & 127;
      sX[bb2*129 + kk] = hst[((size_t)(b0+bb2)*16 + n)*128 + kk];
    }
    __syncthreads();
    #pragma unroll 4
    for (int k = 0; k < 128; ++k){
      float w0 = sW[1][(gq*2+0)*129 + k];
      float w1 = sW[1][(gq*2+1)*129 + k];
      #pragma unroll
      for (int j = 0; j < 4; ++j){
        float xv = sX[(bq*4+j)*129 + k];
        acc[0][j] = fmaf(w0, xv, acc[0][j]);
        acc[1][j] = fmaf(w1, xv, acc[1][j]);
      }
    }
    #pragma unroll
    for (int j = 0; j < 4; ++j){
      size_t base = ((size_t)(b0 + bq*4 + j)*16 + n)*512 + gc*32 + gq*2;
      gates[base + 0] = acc[0][j] + bias0;
      gates[base + 1] = acc[1][j] + bias1;
    }
  }
}

// ---------------- cell update + out head + social partials for next step ----------------
__global__ __launch_bounds__(256) void k_cell(
    const float* __restrict__ gates, float* __restrict__ cst, float* __restrict__ hst,
    const float* __restrict__ Ws, const float* __restrict__ W_ho,
    const float* __restrict__ b_ho, const float* __restrict__ W_out,
    const float* __restrict__ b_out, float* __restrict__ psoc,
    float* __restrict__ y, int t){
  const int n = blockIdx.x >> 4, bt = blockIdx.x & 15;
  const int b0 = bt * 16;
  const int tid = threadIdx.x;
  __shared__ float sH[16][128];
  #pragma unroll
  for (int j = 0; j < 8; ++j){
    int idx = j*256 + tid;
    int bb = idx >> 7, hh = idx & 127;
    size_t gbase = ((size_t)(b0+bb)*16 + n)*512;
    float iv = gates[gbase + hh],      fv = gates[gbase + 128 + hh];
    float gv = gates[gbase + 256 + hh], ov = gates[gbase + 384 + hh];
    size_t saddr = ((size_t)(b0+bb)*16 + n)*128 + hh;
    float cn = sigf(fv) * cst[saddr] + sigf(iv) * tanhf(gv);
    float hn = sigf(ov) * tanhf(cn);
    cst[saddr] = cn; hst[saddr] = hn; sH[bb][hh] = hn;
  }
  __syncthreads();
  { // psoc[n][b][e] = sum_h h_new * Ws[n*128+h][e]
    const int e = tid & 63, bq = tid >> 6;
    float acc[4] = {};
    for (int hh = 0; hh < 128; ++hh){
      float w = Ws[((size_t)n*128 + hh)*64 + e];
      #pragma unroll
      for (int j = 0; j < 4; ++j) acc[j] = fmaf(sH[bq*4+j][hh], w, acc[j]);
    }
    #pragma unroll
    for (int j = 0; j < 4; ++j)
      psoc[((size_t)n*256 + b0 + bq*4 + j)*64 + e] = acc[j];
  }
  __shared__ float sP[16][128];
  { // out head: pre[b][o] = sum_h h_new*W_ho[n][h][o]; sP = W_out[o]*sigmoid(pre+b_ho)
    const int o = tid & 127, half = tid >> 7;
    float acc[8] = {};
    for (int hh = 0; hh < 128; ++hh){
      float w = W_ho[((size_t)n*128 + hh)*128 + o];
      #pragma unroll
      for (int j = 0; j < 8; ++j) acc[j] = fmaf(sH[half + 2*j][hh], w, acc[j]);
    }
    float bho = b_ho[n*128 + o], wo = W_out[o];
    #pragma unroll
    for (int j = 0; j < 8; ++j) sP[half + 2*j][o] = wo * sigf(acc[j] + bho);
  }
  __syncthreads();
  {
    const int bb = tid >> 4, l = tid & 15;
    float sm = 0.f;
    #pragma unroll
    for (int k = 0; k < 8; ++k) sm += sP[bb][l + 16*k];
    #pragma unroll
    for (int m = 8; m >= 1; m >>= 1) sm += __shfl_xor(sm, m, 16);
    if (l == 0) y[((size_t)t*256 + b0 + bb)*16 + n] = sm + b_out[0];
  }
}

extern "C" void kernel_launch(void* const* d_in, const int* in_sizes, int n_in,
                              void* d_out, int out_size, void* d_ws, size_t ws_size,
                              hipStream_t stream){
  const float* x    = (const float*)d_in[0];
  const float* Wd   = (const float*)d_in[1];
  const float* bd   = (const float*)d_in[2];
  const float* Ws   = (const float*)d_in[3];
  const float* bs   = (const float*)d_in[4];
  const float* W_ih = (const float*)d_in[5];
  const float* b_ih = (const float*)d_in[6];
  const float* W_hh = (const float*)d_in[7];
  const float* b_hh = (const float*)d_in[8];
  const float* W_ho = (const float*)d_in[9];
  const float* b_ho = (const float*)d_in[10];
  const float* W_out= (const float*)d_in[11];
  const float* b_out= (const float*)d_in[12];
  float* y = (float*)d_out;

  float* ws = (float*)d_ws;
  float* emb    = ws;                                   // 256*48*16*64 = 12,582,912
  float* hst    = emb + (size_t)256*48*16*64;           // 524,288
  float* cst    = hst + (size_t)256*16*128;             // 524,288
  float* psoc   = cst + (size_t)256*16*128;             // 16*256*64 = 262,144
  float* social = psoc + (size_t)16*256*64;             // 16,384
  float* gates  = social + (size_t)256*64;              // 256*16*512 = 2,097,152

  // zero recurrent state + social partials (ws is poisoned 0xAA)
  hipMemsetAsync(hst, 0, ((size_t)2*256*16*128 + 16*256*64)*sizeof(float), stream);

  k_ds<<<256*48, 256, 0, stream>>>(x, Wd, bd, emb);
  for (int t = 0; t < 48; ++t){
    k_socred<<<64, 256, 0, stream>>>(psoc, bs, social);
    k_gates<<<256, 512, 0, stream>>>(emb, social, hst, W_ih, W_hh, b_ih, b_hh, gates, t);
    k_cell<<<256, 256, 0, stream>>>(gates, cst, hst, Ws, W_ho, b_ho, W_out, b_out, psoc, y, t);
  }
}